// Round 3
// baseline (69.550 us; speedup 1.0000x reference)
//
#include <hip/hip_runtime.h>

// SO(3) exp map (Rodrigues) + translation -> 4x4 matrix.
// Input:  x[B][6] f32  (w = x[:,0:3], t = x[:,3:6])
// Output: out[B][4][4] f32 row-major.
//
// LDS-staged coalesced stores (round 1, 115->68.7us) + raw-barrier schedule:
// __syncthreads() forces `s_waitcnt vmcnt(0)` (drains global stores) at every
// barrier. We replace it with raw s_barrier + minimal waits:
//   barrier 1 (ds_write -> other-wave ds_read): lgkmcnt(0) only
//   barrier 2 (ds_read -> next-tile overwrite): no wait needed (each wave's
//     global_store already waited lgkm for its ds_read data before issuing)
// Next-tile input is prefetched into registers BEFORE this tile's stores in
// program order, so the vmcnt wait for the prefetch never drains the stores.

#define TPB 256
// Padded row length (float4 units) for the LDS transpose buffer.
// P4 % 8 == 2 keeps the read pattern A=(g&3)*P4+(g>>2) at the natural
// 8-lane/bank b128 phasing (same as lane-linear) => no extra conflicts.
#define P4 258

__global__ void __launch_bounds__(TPB)
so3_to_mat_kernel(const float* __restrict__ x, float* __restrict__ out, int n) {
    __shared__ float4 buf[4 * P4];  // buf[s*P4 + r] = float4 #s of tile-row r
    const int t = threadIdx.x;
    const int ntiles = (n + TPB - 1) / TPB;
    const int tstride = gridDim.x;

    int tile = blockIdx.x;
    if (tile >= ntiles) return;  // uniform per block

    // Prefetch first tile's input row (24 B at x + 6*row, 8-B aligned).
    float2 q0 = make_float2(0.f, 0.f), q1 = q0, q2 = q0;
    {
        const int row = tile * TPB + t;
        if (row < n) {
            const float2* xr = reinterpret_cast<const float2*>(x) + 3 * (size_t)row;
            q0 = xr[0]; q1 = xr[1]; q2 = xr[2];
        }
    }

    for (; tile < ntiles; tile += tstride) {
        const int base = tile * TPB;
        const int row = base + t;

        if (row < n) {
            const float wx = q0.x, wy = q0.y, wz = q1.x;
            const float tx = q1.y, ty = q2.x, tz = q2.y;

            const float t2 = wx * wx + wy * wy + wz * wz;
            const bool small = t2 < 1e-8f;

            const float th = sqrtf(small ? 1.0f : t2);
            float s, c;
            sincosf(th, &s, &c);
            const float A  = small ? (1.0f - t2 * (1.0f / 6.0f))  : (s / th);
            const float Bc = small ? (0.5f - t2 * (1.0f / 24.0f)) : ((1.0f - c) / t2);

            const float xx = wx * wx, yy = wy * wy, zz = wz * wz;
            const float xy = wx * wy, xz = wx * wz, yz = wy * wz;

            buf[0 * P4 + t] = make_float4(1.0f - Bc * (yy + zz),
                                          -A * wz + Bc * xy,
                                           A * wy + Bc * xz,
                                          tx);
            buf[1 * P4 + t] = make_float4( A * wz + Bc * xy,
                                          1.0f - Bc * (xx + zz),
                                          -A * wx + Bc * yz,
                                          ty);
            buf[2 * P4 + t] = make_float4(-A * wy + Bc * xz,
                                           A * wx + Bc * yz,
                                          1.0f - Bc * (xx + yy),
                                          tz);
            buf[3 * P4 + t] = make_float4(0.0f, 0.0f, 0.0f, 1.0f);
        }

        // Prefetch next tile's input NOW: these global loads are older than
        // this tile's stores, so waiting on them next iteration needs only
        // vmcnt(<=4) -- the 4 stores stay in flight.
        {
            const int nxt = tile + tstride;
            if (nxt < ntiles) {
                const int row2 = nxt * TPB + t;
                if (row2 < n) {
                    const float2* xr2 = reinterpret_cast<const float2*>(x) + 3 * (size_t)row2;
                    q0 = xr2[0]; q1 = xr2[1]; q2 = xr2[2];
                }
            }
        }

        // Barrier 1: make this wave's ds_writes visible; do NOT drain vmcnt.
        asm volatile("s_waitcnt lgkmcnt(0)" ::: "memory");
        __builtin_amdgcn_s_barrier();
        asm volatile("" ::: "memory");

        // Coalesced write-out: 256 rows * 4 float4 = 1024 lane-consecutive float4.
        const int nrow = min(TPB, n - base);
        float4* ob = reinterpret_cast<float4*>(out) + 4 * (size_t)base;
        if (nrow == TPB) {
            #pragma unroll
            for (int m = 0; m < 4; ++m) {
                const int g = t + TPB * m;
                ob[g] = buf[(g & 3) * P4 + (g >> 2)];
            }
        } else {
            #pragma unroll
            for (int m = 0; m < 4; ++m) {
                const int g = t + TPB * m;
                if (g < 4 * nrow) ob[g] = buf[(g & 3) * P4 + (g >> 2)];
            }
        }

        // Barrier 2: LDS reads of every wave provably complete (their stores
        // issued), so a plain barrier with only a compile-time fence suffices.
        asm volatile("" ::: "memory");
        __builtin_amdgcn_s_barrier();
        asm volatile("" ::: "memory");
    }
}

extern "C" void kernel_launch(void* const* d_in, const int* in_sizes, int n_in,
                              void* d_out, int out_size, void* d_ws, size_t ws_size,
                              hipStream_t stream) {
    const float* x = (const float*)d_in[0];
    float* out = (float*)d_out;
    const int n = in_sizes[0] / 6;  // 4,000,000 rows

    const int ntiles = (n + TPB - 1) / TPB;
    int grid = ntiles < 2048 ? ntiles : 2048;  // 8 blocks/CU (LDS 16.5KB fits)

    so3_to_mat_kernel<<<grid, TPB, 0, stream>>>(x, out, n);
}